// Round 9
// baseline (372.918 us; speedup 1.0000x reference)
//
#include <hip/hip_runtime.h>
#include <hip/hip_bf16.h>
#include <stdint.h>

typedef __attribute__((ext_vector_type(8))) short bf16x8_t;
typedef __attribute__((ext_vector_type(4))) float f32x4_t;
typedef unsigned int u32;
typedef unsigned short u16;
typedef u32 __attribute__((address_space(3))) lds_u32;
typedef u32 __attribute__((address_space(1))) gbl_u32;

#define NUM_H 12
#define NTOK 196
#define NBATCH 64
#define CDIM 768
#define VTS 224   // V^T padded token stride
#define RPS 208   // rpb transposed pad (cols and qr)

__device__ __forceinline__ u16 f2bf(float f) {
    u32 u = __float_as_uint(f);
    u32 r = u + 0x7FFFu + ((u >> 16) & 1u);
    return (u16)(r >> 16);
}

// ---------------- fp32 -> bf16 convert ----------------
__global__ void cvt_kernel(const float* __restrict__ in, u16* __restrict__ out, int n) {
    int n4 = n >> 2;
    for (int i = blockIdx.x * blockDim.x + threadIdx.x; i < n4; i += gridDim.x * blockDim.x) {
        float4 v = ((const float4*)in)[i];
        ushort4 o;
        o.x = f2bf(v.x); o.y = f2bf(v.y); o.z = f2bf(v.z); o.w = f2bf(v.w);
        ((ushort4*)out)[i] = o;
    }
}

// ---------------- rpb expand (transposed): [729][12] -> [12][col 208][qr 208] f32 ----
__global__ void rpb_kernel(const float* __restrict__ table, const int* __restrict__ idx,
                           float* __restrict__ rpbt) {
    int ij = blockIdx.x * 256 + threadIdx.x;
    if (ij < NTOK * NTOK) {
        const int qr = ij / NTOK, col = ij - qr * NTOK;
        const int rp = idx[ij];
        #pragma unroll
        for (int h = 0; h < NUM_H; h++)
            rpbt[((size_t)h * RPS + col) * RPS + qr] = table[rp * NUM_H + h];
    }
}

// ---------------- GEMM: C[M,N] = A[M,K] @ W[N,K]^T  (bf16 in, epilogue per mode) ----
// Grid: 1D, 8*13*nbn blocks. xcd=bid&7, bm=xcd*13+(i%13), bn=i/13  ->  each XCD
// owns a 13-block bm-strip (2.5 MB of A, L2-resident) and streams W panels.
// K-loop: TRIPLE-buffered LDS (48 KB), TWO stages in flight, vmcnt(8):
// r8 showed vmcnt(4)/dbuf leaves every K-step exposed to (load_latency - 80cy).
// launch_bounds(256,3): 3 blocks/CU (LDS 48KB*3=144KB <=160KB).
__global__ __launch_bounds__(256, 3) void gemm_kernel(
    const u16* __restrict__ A, const u16* __restrict__ W, int K, int mode,
    const float* __restrict__ bias_q, const float* __restrict__ bias_v,
    u16* __restrict__ oq, u16* __restrict__ ok, u16* __restrict__ ovt,
    const float* __restrict__ pbias, float* __restrict__ of) {
    __shared__ __align__(16) u16 lds[3][2][4096]; // [buf][A/B][128*32]
    const int tid = threadIdx.x;
    const int wave = tid >> 6, lane = tid & 63;
    const int wr = wave >> 1, wc = wave & 1;
    const int bid = blockIdx.x;
    const int xcd = bid & 7, i = bid >> 3;
    const int i13 = i / 13;
    const int bm = xcd * 13 + (i - i13 * 13);
    const int bn = i13;
    if (bm >= 98) return; // pad blocks (uniform per block, before any barrier)

    f32x4_t acc[4][4];
    #pragma unroll
    for (int ii = 0; ii < 4; ii++)
        #pragma unroll
        for (int jj = 0; jj < 4; jj++) acc[ii][jj] = f32x4_t{0.f, 0.f, 0.f, 0.f};

    auto stage = [&](int buf, int kt) {
        const int k0 = kt * 32;
        const int su = (lane & 3) ^ ((lane >> 2) & 3); // swizzled source 16B-unit
        #pragma unroll
        for (int c2 = 0; c2 < 2; c2++) {
            const int c = wave * 2 + c2;
            {
                const int row = bm * 128 + c * 16 + (lane >> 2);
                const u16* src = A + (size_t)row * K + k0 + su * 8;
                __builtin_amdgcn_global_load_lds((gbl_u32*)src, (lds_u32*)&lds[buf][0][c * 512], 16, 0, 0);
            }
            {
                const int row = bn * 128 + c * 16 + (lane >> 2);
                const u16* src = W + (size_t)row * K + k0 + su * 8;
                __builtin_amdgcn_global_load_lds((gbl_u32*)src, (lds_u32*)&lds[buf][1][c * 512], 16, 0, 0);
            }
        }
    };

    const int NKT = K >> 5; // 24
    stage(0, 0);
    if (NKT > 1) stage(1, 1);
    int buf = 0, nbuf = 2;
    for (int kt = 0; kt < NKT; ++kt) {
        if (kt + 2 < NKT) {
            stage(nbuf, kt + 2);
            nbuf = (nbuf == 2) ? 0 : nbuf + 1;
            // oldest 4 (stage kt) done; stages kt+1, kt+2 (8 loads) stay in flight
            asm volatile("s_waitcnt vmcnt(8)" ::: "memory");
        } else if (kt + 1 < NKT) {
            asm volatile("s_waitcnt vmcnt(4)" ::: "memory");
        } else {
            asm volatile("s_waitcnt vmcnt(0)" ::: "memory");
        }
        __builtin_amdgcn_s_barrier(); // everyone's stage(kt) landed
        bf16x8_t af[4], bfr[4];
        #pragma unroll
        for (int mt = 0; mt < 4; mt++) {
            const int r = wr * 64 + mt * 16 + (lane & 15);
            const int u = (lane >> 4) ^ (r & 3);
            af[mt] = *(const bf16x8_t*)&lds[buf][0][r * 32 + u * 8];
        }
        #pragma unroll
        for (int nt = 0; nt < 4; nt++) {
            const int r = wc * 64 + nt * 16 + (lane & 15);
            const int u = (lane >> 4) ^ (r & 3);
            bfr[nt] = *(const bf16x8_t*)&lds[buf][1][r * 32 + u * 8];
        }
        #pragma unroll
        for (int mt = 0; mt < 4; mt++)
            #pragma unroll
            for (int nt = 0; nt < 4; nt++)
                acc[mt][nt] = __builtin_amdgcn_mfma_f32_16x16x32_bf16(af[mt], bfr[nt], acc[mt][nt], 0, 0, 0);
        asm volatile("s_waitcnt lgkmcnt(0)" ::: "memory"); // my reads of buf done
        __builtin_amdgcn_s_barrier();                       // all waves done reading buf
        buf = (buf == 2) ? 0 : buf + 1;
    }

    const int g = lane >> 4;
    if (mode == 0) {
        #pragma unroll
        for (int nt = 0; nt < 4; nt++) {
            const int n = bn * 128 + wc * 64 + nt * 16 + (lane & 15);
            const int which = n / CDIM;
            const int rem = n - which * CDIM;
            const int hh = rem >> 6, d = rem & 63;
            const float bias = (which == 0) ? bias_q[rem] : (which == 2 ? bias_v[rem] : 0.f);
            #pragma unroll
            for (int mt = 0; mt < 4; mt++) {
                const int m0 = bm * 128 + wr * 64 + mt * 16 + 4 * g;
                const int bb = m0 / NTOK, t0 = m0 - bb * NTOK; // r=0..3 stay in-row (196%4==0)
                if (which == 2) {
                    ushort4 vv;
                    vv.x = f2bf(acc[mt][nt][0] + bias);
                    vv.y = f2bf(acc[mt][nt][1] + bias);
                    vv.z = f2bf(acc[mt][nt][2] + bias);
                    vv.w = f2bf(acc[mt][nt][3] + bias);
                    *(ushort4*)&ovt[(((size_t)bb * NUM_H + hh) * 64 + d) * VTS + t0] = vv;
                } else {
                    u16* dst = (which == 0) ? oq : ok;
                    #pragma unroll
                    for (int r = 0; r < 4; r++) {
                        float v = acc[mt][nt][r] + bias;
                        if (which == 0) v *= 0.125f;
                        dst[(((size_t)bb * NUM_H + hh) * NTOK + t0 + r) * 64 + d] = f2bf(v);
                    }
                }
            }
        }
    } else {
        #pragma unroll
        for (int mt = 0; mt < 4; mt++) {
            #pragma unroll
            for (int r = 0; r < 4; r++) {
                const int m = bm * 128 + wr * 64 + mt * 16 + 4 * g + r;
                #pragma unroll
                for (int nt = 0; nt < 4; nt++) {
                    const int n = bn * 128 + wc * 64 + nt * 16 + (lane & 15);
                    of[(size_t)m * CDIM + n] = acc[mt][nt][r] + pbias[n];
                }
            }
        }
    }
}

// ---------------- attention: 4 waves/block, each wave TWO q-tiles of one (b,h) ----
// K/V fragments loaded once per wave feed BOTH tiles' MFMAs.
// launch_bounds(256,4): VGPR cap 128 (r8 measured 112 -> fits), 4 blocks/CU,
// doubling r8's 18% occupancy. (r7 lesson: cap 64 spilled; cap 128 won't.)
// Decode: x=bid&7 (XCD), j=(bid>>3)*4+wave in [0,672), bh=x+8*(j/7), m=j%7,
// tiles qt=2m, 2m+1 (m=6: only the even tile exists).
__global__ __launch_bounds__(256, 4) void attn_kernel(
    const u16* __restrict__ Q, const u16* __restrict__ Kg, const u16* __restrict__ Vt,
    const float* __restrict__ rpbt, u16* __restrict__ O) {
    __shared__ __align__(16) u16 Ps[4][2][16 * 64];
    const int lane = threadIdx.x & 63, wave = threadIdx.x >> 6;
    const int x = blockIdx.x & 7, j = (blockIdx.x >> 3) * 4 + wave;
    const int j7 = j / 7;
    const int bh = x + 8 * j7;
    const int m = j - 7 * j7;
    const int qtA = 2 * m;
    const bool HASB = (m < 6);
    const int b = bh / NUM_H, h = bh - b * NUM_H;
    const u16* Qb = Q + (size_t)bh * NTOK * 64;
    const u16* Kb = Kg + (size_t)bh * NTOK * 64;
    const u16* Vb = Vt + (size_t)bh * 64 * VTS;
    const int g = lane >> 4, lc = lane & 15;
    const float* rpbc[2];
    rpbc[0] = rpbt + ((size_t)h * RPS + lc) * RPS + qtA * 16 + 4 * g; // + nt*16*RPS
    rpbc[1] = HASB ? rpbc[0] + 16 : rpbc[0];

    // Q fragments (A operand) for both tiles: row = (qtA+t)*16+lc
    bf16x8_t qf[2][2];
    #pragma unroll
    for (int t = 0; t < 2; t++) {
        const int qrow_f = (qtA + t) * 16 + lc;
        #pragma unroll
        for (int kk = 0; kk < 2; kk++) {
            if (qrow_f < NTOK) qf[t][kk] = *(const bf16x8_t*)(Qb + qrow_f * 64 + kk * 32 + g * 8);
            else qf[t][kk] = bf16x8_t{0, 0, 0, 0, 0, 0, 0, 0};
        }
    }
    // S = Q K^T — K frags loaded ONCE, feed both tiles
    f32x4_t s[2][13];
    #pragma unroll
    for (int t = 0; t < 2; t++)
        #pragma unroll
        for (int nt = 0; nt < 13; nt++) s[t][nt] = f32x4_t{0.f, 0.f, 0.f, 0.f};
    #pragma unroll
    for (int nt = 0; nt < 13; nt++) {
        #pragma unroll
        for (int kk = 0; kk < 2; kk++) {
            bf16x8_t kf = *(const bf16x8_t*)(Kb + (nt * 16 + lc) * 64 + kk * 32 + g * 8);
            s[0][nt] = __builtin_amdgcn_mfma_f32_16x16x32_bf16(qf[0][kk], kf, s[0][nt], 0, 0, 0);
            if (HASB)
                s[1][nt] = __builtin_amdgcn_mfma_f32_16x16x32_bf16(qf[1][kk], kf, s[1][nt], 0, 0, 0);
        }
    }
    // + rpb, mask, row max, softmax (per tile)
    float inv[2][4];
    #pragma unroll
    for (int t = 0; t < 2; t++) {
        if (t == 1 && !HASB) break;
        float mx[4] = {-3e38f, -3e38f, -3e38f, -3e38f};
        #pragma unroll
        for (int nt = 0; nt < 13; nt++) {
            const int col = nt * 16 + lc;
            const float4 rp = *(const float4*)(rpbc[t] + nt * 16 * RPS);
            const float rpv[4] = {rp.x, rp.y, rp.z, rp.w};
            #pragma unroll
            for (int r = 0; r < 4; r++) {
                const int qr = (qtA + t) * 16 + 4 * g + r;
                float v;
                if (col < NTOK && qr < NTOK) v = s[t][nt][r] + rpv[r];
                else v = -1e30f;
                s[t][nt][r] = v;
                mx[r] = fmaxf(mx[r], v);
            }
        }
        #pragma unroll
        for (int r = 0; r < 4; r++) {
            mx[r] = fmaxf(mx[r], __shfl_xor(mx[r], 1));
            mx[r] = fmaxf(mx[r], __shfl_xor(mx[r], 2));
            mx[r] = fmaxf(mx[r], __shfl_xor(mx[r], 4));
            mx[r] = fmaxf(mx[r], __shfl_xor(mx[r], 8));
        }
        float sm[4] = {0.f, 0.f, 0.f, 0.f};
        #pragma unroll
        for (int nt = 0; nt < 13; nt++)
            #pragma unroll
            for (int r = 0; r < 4; r++) {
                float p = __expf(s[t][nt][r] - mx[r]);
                s[t][nt][r] = p;
                sm[r] += p;
            }
        #pragma unroll
        for (int r = 0; r < 4; r++) {
            sm[r] += __shfl_xor(sm[r], 1);
            sm[r] += __shfl_xor(sm[r], 2);
            sm[r] += __shfl_xor(sm[r], 4);
            sm[r] += __shfl_xor(sm[r], 8);
            inv[t][r] = 1.f / sm[r];
        }
    }

    // O = P V via Ps LDS transpose; V frags loaded ONCE per (kc,ks,dt), feed both tiles
    f32x4_t o4[2][4];
    #pragma unroll
    for (int t = 0; t < 2; t++)
        #pragma unroll
        for (int dt = 0; dt < 4; dt++) o4[t][dt] = f32x4_t{0.f, 0.f, 0.f, 0.f};
    for (int kc = 0; kc < 4; kc++) {
        #pragma unroll
        for (int ntl = 0; ntl < 4; ntl++) {
            const int nt = kc * 4 + ntl;
            const int kl = ntl * 16 + lc;
            #pragma unroll
            for (int r = 0; r < 4; r++) {
                const int rr = 4 * g + r;
                const int off = rr * 64 + (((kl >> 3) ^ (rr & 7)) << 3) + (kl & 7);
                Ps[wave][0][off] = (nt < 13) ? f2bf(s[0][nt][r]) : (u16)0;
                if (HASB) Ps[wave][1][off] = (nt < 13) ? f2bf(s[1][nt][r]) : (u16)0;
            }
        }
        asm volatile("s_waitcnt lgkmcnt(0)" ::: "memory");
        const int nsteps = (kc < 3) ? 2 : 1;
        for (int ks = 0; ks < nsteps; ks++) {
            const int rr = lc;
            const int u = (ks * 4 + g) ^ (rr & 7);
            bf16x8_t pfA = *(const bf16x8_t*)&Ps[wave][0][rr * 64 + u * 8];
            bf16x8_t pfB;
            if (HASB) pfB = *(const bf16x8_t*)&Ps[wave][1][rr * 64 + u * 8];
            #pragma unroll
            for (int dt = 0; dt < 4; dt++) {
                const int dcol = dt * 16 + lc;
                const int kb = kc * 64 + ks * 32 + g * 8;
                bf16x8_t vf = *(const bf16x8_t*)(Vb + dcol * VTS + kb);
                o4[0][dt] = __builtin_amdgcn_mfma_f32_16x16x32_bf16(pfA, vf, o4[0][dt], 0, 0, 0);
                if (HASB)
                    o4[1][dt] = __builtin_amdgcn_mfma_f32_16x16x32_bf16(pfB, vf, o4[1][dt], 0, 0, 0);
            }
        }
        asm volatile("" ::: "memory"); // order next kc's Ps writes after this kc's reads
    }
    // epilogue: Out[b][qr][h*64+d] bf16
    #pragma unroll
    for (int t = 0; t < 2; t++) {
        if (t == 1 && !HASB) break;
        #pragma unroll
        for (int dt = 0; dt < 4; dt++)
            #pragma unroll
            for (int r = 0; r < 4; r++) {
                const int qr = (qtA + t) * 16 + 4 * g + r;
                if (qr < NTOK)
                    O[((size_t)b * NTOK + qr) * CDIM + h * 64 + dt * 16 + lc] =
                        f2bf(o4[t][dt][r] * inv[t][r]);
            }
    }
}

extern "C" void kernel_launch(void* const* d_in, const int* in_sizes, int n_in,
                              void* d_out, int out_size, void* d_ws, size_t ws_size,
                              hipStream_t stream) {
    const float* x = (const float*)d_in[0];
    const float* qkvw = (const float*)d_in[1];
    const float* qb = (const float*)d_in[2];
    const float* vb = (const float*)d_in[3];
    const float* rpbt = (const float*)d_in[4];
    const int* rpi = (const int*)d_in[5];
    const float* pw = (const float*)d_in[6];
    const float* pb = (const float*)d_in[7];
    float* out = (float*)d_out;

    char* ws = (char*)d_ws;
    size_t off = 0;
    auto alloc = [&](size_t bytes) {
        void* p = ws + off;
        off += (bytes + 255) & ~(size_t)255;
        return p;
    };
    const size_t MROWS = 12544; // 64*196
    u16* xbf = (u16*)alloc(MROWS * 768 * 2);
    u16* wbf = (u16*)alloc((size_t)2304 * 768 * 2);
    u16* pwbf = (u16*)alloc((size_t)768 * 768 * 2);
    u16* qws = (u16*)alloc(MROWS * 768 * 2);
    u16* kws = (u16*)alloc(MROWS * 768 * 2);
    u16* vtws = (u16*)alloc((size_t)768 * 64 * VTS * 2 + 256); // V^T [bh][64][VTS] (+slack)
    u16* aout = (u16*)alloc(MROWS * 768 * 2);
    float* rpbm = (float*)alloc((size_t)NUM_H * RPS * RPS * 4 + 256); // transposed [h][col][qr] (+slack)

    cvt_kernel<<<2048, 256, 0, stream>>>(x, xbf, 12544 * 768);
    cvt_kernel<<<1024, 256, 0, stream>>>(qkvw, wbf, 2304 * 768);
    cvt_kernel<<<512, 256, 0, stream>>>(pw, pwbf, 768 * 768);
    rpb_kernel<<<(196 * 196 + 255) / 256, 256, 0, stream>>>(rpbt, rpi, rpbm);
    // XCD-swizzled 1D grids: 8 XCDs * 13 bm-strip * nbn  (bm>=98 pad blocks exit)
    gemm_kernel<<<8 * 13 * 18, 256, 0, stream>>>(xbf, wbf, 768, 0, qb, vb, qws, kws, vtws, nullptr, nullptr);
    // 8 XCDs * 168 blocks; each block = 4 waves, each wave = 2 q-tiles of one bh
    attn_kernel<<<1344, 256, 0, stream>>>(qws, kws, vtws, rpbm, aout);
    gemm_kernel<<<8 * 13 * 6, 256, 0, stream>>>(aout, pwbf, 768, 1, nullptr, nullptr, nullptr, nullptr, nullptr, pb, out);
}

// Round 10
// 184.192 us; speedup vs baseline: 2.0246x; 2.0246x over previous
//
#include <hip/hip_runtime.h>
#include <hip/hip_bf16.h>
#include <stdint.h>

typedef __attribute__((ext_vector_type(8))) short bf16x8_t;
typedef __attribute__((ext_vector_type(4))) float f32x4_t;
typedef unsigned int u32;
typedef unsigned short u16;
typedef u32 __attribute__((address_space(3))) lds_u32;
typedef u32 __attribute__((address_space(1))) gbl_u32;

#define NUM_H 12
#define NTOK 196
#define NBATCH 64
#define CDIM 768
#define VTS 224    // V^T global token stride
#define VLS 232    // V^T LDS token stride (bank-friendly)
#define RPS 208    // rpb transposed pad (cols and qr)

__device__ __forceinline__ u16 f2bf(float f) {
    u32 u = __float_as_uint(f);
    u32 r = u + 0x7FFFu + ((u >> 16) & 1u);
    return (u16)(r >> 16);
}

// ---------------- fp32 -> bf16 convert ----------------
__global__ void cvt_kernel(const float* __restrict__ in, u16* __restrict__ out, int n) {
    int n4 = n >> 2;
    for (int i = blockIdx.x * blockDim.x + threadIdx.x; i < n4; i += gridDim.x * blockDim.x) {
        float4 v = ((const float4*)in)[i];
        ushort4 o;
        o.x = f2bf(v.x); o.y = f2bf(v.y); o.z = f2bf(v.z); o.w = f2bf(v.w);
        ((ushort4*)out)[i] = o;
    }
}

// ---------------- rpb expand (transposed): [729][12] -> [12][col 208][qr 208] f32 ----
__global__ void rpb_kernel(const float* __restrict__ table, const int* __restrict__ idx,
                           float* __restrict__ rpbt) {
    int ij = blockIdx.x * 256 + threadIdx.x;
    if (ij < NTOK * NTOK) {
        const int qr = ij / NTOK, col = ij - qr * NTOK;
        const int rp = idx[ij];
        #pragma unroll
        for (int h = 0; h < NUM_H; h++)
            rpbt[((size_t)h * RPS + col) * RPS + qr] = table[rp * NUM_H + h];
    }
}

// ---------------- GEMM: C[M,N] = A[M,K] @ W[N,K]^T  (bf16 in, epilogue per mode) ----
// XCD bm-strip grid; triple-buffered LDS, two stages in flight (vmcnt(8)).
__global__ __launch_bounds__(256, 3) void gemm_kernel(
    const u16* __restrict__ A, const u16* __restrict__ W, int K, int mode,
    const float* __restrict__ bias_q, const float* __restrict__ bias_v,
    u16* __restrict__ oq, u16* __restrict__ ok, u16* __restrict__ ovt,
    const float* __restrict__ pbias, float* __restrict__ of) {
    __shared__ __align__(16) u16 lds[3][2][4096]; // [buf][A/B][128*32]
    const int tid = threadIdx.x;
    const int wave = tid >> 6, lane = tid & 63;
    const int wr = wave >> 1, wc = wave & 1;
    const int bid = blockIdx.x;
    const int xcd = bid & 7, i = bid >> 3;
    const int i13 = i / 13;
    const int bm = xcd * 13 + (i - i13 * 13);
    const int bn = i13;
    if (bm >= 98) return; // pad blocks (uniform per block, before any barrier)

    f32x4_t acc[4][4];
    #pragma unroll
    for (int ii = 0; ii < 4; ii++)
        #pragma unroll
        for (int jj = 0; jj < 4; jj++) acc[ii][jj] = f32x4_t{0.f, 0.f, 0.f, 0.f};

    auto stage = [&](int buf, int kt) {
        const int k0 = kt * 32;
        const int su = (lane & 3) ^ ((lane >> 2) & 3); // swizzled source 16B-unit
        #pragma unroll
        for (int c2 = 0; c2 < 2; c2++) {
            const int c = wave * 2 + c2;
            {
                const int row = bm * 128 + c * 16 + (lane >> 2);
                const u16* src = A + (size_t)row * K + k0 + su * 8;
                __builtin_amdgcn_global_load_lds((gbl_u32*)src, (lds_u32*)&lds[buf][0][c * 512], 16, 0, 0);
            }
            {
                const int row = bn * 128 + c * 16 + (lane >> 2);
                const u16* src = W + (size_t)row * K + k0 + su * 8;
                __builtin_amdgcn_global_load_lds((gbl_u32*)src, (lds_u32*)&lds[buf][1][c * 512], 16, 0, 0);
            }
        }
    };

    const int NKT = K >> 5; // 24
    stage(0, 0);
    if (NKT > 1) stage(1, 1);
    int buf = 0, nbuf = 2;
    for (int kt = 0; kt < NKT; ++kt) {
        if (kt + 2 < NKT) {
            stage(nbuf, kt + 2);
            nbuf = (nbuf == 2) ? 0 : nbuf + 1;
            asm volatile("s_waitcnt vmcnt(8)" ::: "memory");
        } else if (kt + 1 < NKT) {
            asm volatile("s_waitcnt vmcnt(4)" ::: "memory");
        } else {
            asm volatile("s_waitcnt vmcnt(0)" ::: "memory");
        }
        __builtin_amdgcn_s_barrier(); // everyone's stage(kt) landed
        bf16x8_t af[4], bfr[4];
        #pragma unroll
        for (int mt = 0; mt < 4; mt++) {
            const int r = wr * 64 + mt * 16 + (lane & 15);
            const int u = (lane >> 4) ^ (r & 3);
            af[mt] = *(const bf16x8_t*)&lds[buf][0][r * 32 + u * 8];
        }
        #pragma unroll
        for (int nt = 0; nt < 4; nt++) {
            const int r = wc * 64 + nt * 16 + (lane & 15);
            const int u = (lane >> 4) ^ (r & 3);
            bfr[nt] = *(const bf16x8_t*)&lds[buf][1][r * 32 + u * 8];
        }
        #pragma unroll
        for (int mt = 0; mt < 4; mt++)
            #pragma unroll
            for (int nt = 0; nt < 4; nt++)
                acc[mt][nt] = __builtin_amdgcn_mfma_f32_16x16x32_bf16(af[mt], bfr[nt], acc[mt][nt], 0, 0, 0);
        asm volatile("s_waitcnt lgkmcnt(0)" ::: "memory"); // my reads of buf done
        __builtin_amdgcn_s_barrier();                       // all waves done reading buf
        buf = (buf == 2) ? 0 : buf + 1;
    }

    const int g = lane >> 4;
    if (mode == 0) {
        #pragma unroll
        for (int nt = 0; nt < 4; nt++) {
            const int n = bn * 128 + wc * 64 + nt * 16 + (lane & 15);
            const int which = n / CDIM;
            const int rem = n - which * CDIM;
            const int hh = rem >> 6, d = rem & 63;
            const float bias = (which == 0) ? bias_q[rem] : (which == 2 ? bias_v[rem] : 0.f);
            #pragma unroll
            for (int mt = 0; mt < 4; mt++) {
                const int m0 = bm * 128 + wr * 64 + mt * 16 + 4 * g;
                const int bb = m0 / NTOK, t0 = m0 - bb * NTOK; // r=0..3 stay in-row (196%4==0)
                if (which == 2) {
                    ushort4 vv;
                    vv.x = f2bf(acc[mt][nt][0] + bias);
                    vv.y = f2bf(acc[mt][nt][1] + bias);
                    vv.z = f2bf(acc[mt][nt][2] + bias);
                    vv.w = f2bf(acc[mt][nt][3] + bias);
                    *(ushort4*)&ovt[(((size_t)bb * NUM_H + hh) * 64 + d) * VTS + t0] = vv;
                } else {
                    u16* dst = (which == 0) ? oq : ok;
                    #pragma unroll
                    for (int r = 0; r < 4; r++) {
                        float v = acc[mt][nt][r] + bias;
                        if (which == 0) v *= 0.125f;
                        dst[(((size_t)bb * NUM_H + hh) * NTOK + t0 + r) * 64 + d] = f2bf(v);
                    }
                }
            }
        }
    } else {
        #pragma unroll
        for (int mt = 0; mt < 4; mt++) {
            #pragma unroll
            for (int r = 0; r < 4; r++) {
                const int m = bm * 128 + wr * 64 + mt * 16 + 4 * g + r;
                #pragma unroll
                for (int nt = 0; nt < 4; nt++) {
                    const int n = bn * 128 + wc * 64 + nt * 16 + (lane & 15);
                    of[(size_t)m * CDIM + n] = acc[mt][nt][r] + pbias[n];
                }
            }
        }
    }
}

// ---------------- attention: one block per (b,h); K+V^T DMA-staged in LDS ----------
// r9 lesson: unified VGPR+AGPR footprint (~216/wave) caps residency at 2 waves/SIMD;
// launch-bounds tricks only cause spills. So instead remove registers from the
// memory path: global_load_lds DMA stages K (swizzled rows) and V^T (stride 232)
// once per bh, shared by 4 waves; QK^T/PV operands become ds_reads. Per-wave
// global loads drop to Q(4)+rpb(13) per tile. LDS 72.7KB -> 2 blocks/CU.
// Grid 768 = 8 XCD x 96 (bh = (bid&7) + 8*(bid>>3)). Wave w does qt = w, w+4, w+8 (+12 for w=0).
__global__ __launch_bounds__(256, 2) void attn_kernel(
    const u16* __restrict__ Q, const u16* __restrict__ Kg, const u16* __restrict__ Vt,
    const float* __restrict__ rpbt, u16* __restrict__ O) {
    __shared__ __align__(16) u16 Ks[208 * 64];   // 26624 B, swizzled rows
    __shared__ __align__(16) u16 Vs[64 * VLS];   // 29696 B = 29 chunks
    __shared__ __align__(16) u16 Ps[4][16 * 64]; // per-wave P transpose buffer
    const int lane = threadIdx.x & 63, wave = threadIdx.x >> 6;
    const int bh = (blockIdx.x & 7) + 8 * (blockIdx.x >> 3);
    const int b = bh / NUM_H, h = bh - b * NUM_H;
    const u16* Qb = Q + (size_t)bh * NTOK * 64;
    const u16* Kb = Kg + (size_t)bh * NTOK * 64;
    const u16* Vgb = Vt + (size_t)bh * 64 * VTS;
    const int g = lane >> 4, lc = lane & 15;

    // ---- DMA staging: 26 K-chunks + 29 V-chunks of 1KB, round-robin over waves ----
    for (int c = wave; c < 26 + 29; c += 4) {
        if (c < 26) {
            // K chunk: 8 rows x 8 16B-units; LDS linear, source pre-swizzled
            const int row = c * 8 + (lane >> 3);
            const int u = lane & 7;
            const int srow = (row < NTOK) ? row : (NTOK - 1); // clamp pad rows (masked later)
            const u16* src = Kb + srow * 64 + ((u ^ (row & 7)) << 3);
            __builtin_amdgcn_global_load_lds((gbl_u32*)src, (lds_u32*)&Ks[c * 512], 16, 0, 0);
        } else {
            // V chunk: linear bytes into [64][VLS] (stride 464B); source mapped per lane
            const int p = (c - 26) * 1024 + lane * 16; // byte offset in Vs
            const int d = p / (VLS * 2);
            const int off = p - d * (VLS * 2);
            const u16* src = (off < VTS * 2) ? (Vgb + d * VTS + (off >> 1)) : Vgb; // clamp pad tail
            __builtin_amdgcn_global_load_lds((gbl_u32*)src, (lds_u32*)((char*)Vs + (c - 26) * 1024), 16, 0, 0);
        }
    }
    asm volatile("s_waitcnt vmcnt(0)" ::: "memory");
    __syncthreads();

    // ---- per-wave tile loop ----
    for (int qt = wave; qt < 13; qt += 4) {
        const float* rpbc = rpbt + ((size_t)h * RPS + lc) * RPS + qt * 16 + 4 * g;
        // Q fragments
        bf16x8_t qf[2];
        const int qrow_f = qt * 16 + lc;
        #pragma unroll
        for (int kk = 0; kk < 2; kk++) {
            if (qrow_f < NTOK) qf[kk] = *(const bf16x8_t*)(Qb + qrow_f * 64 + kk * 32 + g * 8);
            else qf[kk] = bf16x8_t{0, 0, 0, 0, 0, 0, 0, 0};
        }
        // S = Q K^T from LDS
        f32x4_t s[13];
        #pragma unroll
        for (int nt = 0; nt < 13; nt++) s[nt] = f32x4_t{0.f, 0.f, 0.f, 0.f};
        #pragma unroll
        for (int nt = 0; nt < 13; nt++) {
            #pragma unroll
            for (int kk = 0; kk < 2; kk++) {
                const int kr = nt * 16 + lc;
                const int u = (kk * 4 + g) ^ (kr & 7);
                bf16x8_t kf = *(const bf16x8_t*)&Ks[kr * 64 + u * 8];
                s[nt] = __builtin_amdgcn_mfma_f32_16x16x32_bf16(qf[kk], kf, s[nt], 0, 0, 0);
            }
        }
        // + rpb, mask, row max
        float mx[4] = {-3e38f, -3e38f, -3e38f, -3e38f};
        #pragma unroll
        for (int nt = 0; nt < 13; nt++) {
            const int col = nt * 16 + lc;
            const float4 rp = *(const float4*)(rpbc + nt * 16 * RPS);
            const float rpv[4] = {rp.x, rp.y, rp.z, rp.w};
            #pragma unroll
            for (int r = 0; r < 4; r++) {
                const int qr = qt * 16 + 4 * g + r;
                float v;
                if (col < NTOK && qr < NTOK) v = s[nt][r] + rpv[r];
                else v = -1e30f;
                s[nt][r] = v;
                mx[r] = fmaxf(mx[r], v);
            }
        }
        #pragma unroll
        for (int r = 0; r < 4; r++) {
            mx[r] = fmaxf(mx[r], __shfl_xor(mx[r], 1));
            mx[r] = fmaxf(mx[r], __shfl_xor(mx[r], 2));
            mx[r] = fmaxf(mx[r], __shfl_xor(mx[r], 4));
            mx[r] = fmaxf(mx[r], __shfl_xor(mx[r], 8));
        }
        float sm[4] = {0.f, 0.f, 0.f, 0.f};
        #pragma unroll
        for (int nt = 0; nt < 13; nt++)
            #pragma unroll
            for (int r = 0; r < 4; r++) {
                float p = __expf(s[nt][r] - mx[r]);
                s[nt][r] = p;
                sm[r] += p;
            }
        float inv[4];
        #pragma unroll
        for (int r = 0; r < 4; r++) {
            sm[r] += __shfl_xor(sm[r], 1);
            sm[r] += __shfl_xor(sm[r], 2);
            sm[r] += __shfl_xor(sm[r], 4);
            sm[r] += __shfl_xor(sm[r], 8);
            inv[r] = 1.f / sm[r];
        }

        // O = P V via Ps LDS transpose; V from LDS (stride VLS)
        f32x4_t o4[4];
        #pragma unroll
        for (int dt = 0; dt < 4; dt++) o4[dt] = f32x4_t{0.f, 0.f, 0.f, 0.f};
        for (int kc = 0; kc < 4; kc++) {
            #pragma unroll
            for (int ntl = 0; ntl < 4; ntl++) {
                const int nt = kc * 4 + ntl;
                const int kl = ntl * 16 + lc;
                #pragma unroll
                for (int r = 0; r < 4; r++) {
                    const int rr = 4 * g + r;
                    u16 pv = 0;
                    if (nt < 13) pv = f2bf(s[nt][r]);
                    Ps[wave][rr * 64 + (((kl >> 3) ^ (rr & 7)) << 3) + (kl & 7)] = pv;
                }
            }
            asm volatile("s_waitcnt lgkmcnt(0)" ::: "memory");
            const int nsteps = (kc < 3) ? 2 : 1;
            for (int ks = 0; ks < nsteps; ks++) {
                const int rr = lc;
                const int u = (ks * 4 + g) ^ (rr & 7);
                bf16x8_t pf = *(const bf16x8_t*)&Ps[wave][rr * 64 + u * 8];
                #pragma unroll
                for (int dt = 0; dt < 4; dt++) {
                    const int dcol = dt * 16 + lc;
                    const int kb = kc * 64 + ks * 32 + g * 8;
                    bf16x8_t vf = *(const bf16x8_t*)&Vs[dcol * VLS + kb];
                    o4[dt] = __builtin_amdgcn_mfma_f32_16x16x32_bf16(pf, vf, o4[dt], 0, 0, 0);
                }
            }
            asm volatile("" ::: "memory"); // order next kc's Ps writes after this kc's reads
        }
        // epilogue: Out[b][qr][h*64+d] bf16
        #pragma unroll
        for (int dt = 0; dt < 4; dt++)
            #pragma unroll
            for (int r = 0; r < 4; r++) {
                const int qr = qt * 16 + 4 * g + r;
                if (qr < NTOK)
                    O[((size_t)b * NTOK + qr) * CDIM + h * 64 + dt * 16 + lc] = f2bf(o4[dt][r] * inv[r]);
            }
    }
}

extern "C" void kernel_launch(void* const* d_in, const int* in_sizes, int n_in,
                              void* d_out, int out_size, void* d_ws, size_t ws_size,
                              hipStream_t stream) {
    const float* x = (const float*)d_in[0];
    const float* qkvw = (const float*)d_in[1];
    const float* qb = (const float*)d_in[2];
    const float* vb = (const float*)d_in[3];
    const float* rpbt = (const float*)d_in[4];
    const int* rpi = (const int*)d_in[5];
    const float* pw = (const float*)d_in[6];
    const float* pb = (const float*)d_in[7];
    float* out = (float*)d_out;

    char* ws = (char*)d_ws;
    size_t off = 0;
    auto alloc = [&](size_t bytes) {
        void* p = ws + off;
        off += (bytes + 255) & ~(size_t)255;
        return p;
    };
    const size_t MROWS = 12544; // 64*196
    u16* xbf = (u16*)alloc(MROWS * 768 * 2);
    u16* wbf = (u16*)alloc((size_t)2304 * 768 * 2);
    u16* pwbf = (u16*)alloc((size_t)768 * 768 * 2);
    u16* qws = (u16*)alloc(MROWS * 768 * 2);
    u16* kws = (u16*)alloc(MROWS * 768 * 2);
    u16* vtws = (u16*)alloc((size_t)768 * 64 * VTS * 2 + 256); // V^T [bh][64][VTS] (+slack)
    u16* aout = (u16*)alloc(MROWS * 768 * 2);
    float* rpbm = (float*)alloc((size_t)NUM_H * RPS * RPS * 4 + 256); // transposed [h][col][qr] (+slack)

    cvt_kernel<<<2048, 256, 0, stream>>>(x, xbf, 12544 * 768);
    cvt_kernel<<<1024, 256, 0, stream>>>(qkvw, wbf, 2304 * 768);
    cvt_kernel<<<512, 256, 0, stream>>>(pw, pwbf, 768 * 768);
    rpb_kernel<<<(196 * 196 + 255) / 256, 256, 0, stream>>>(rpbt, rpi, rpbm);
    // XCD-swizzled 1D grids: 8 XCDs * 13 bm-strip * nbn  (bm>=98 pad blocks exit)
    gemm_kernel<<<8 * 13 * 18, 256, 0, stream>>>(xbf, wbf, 768, 0, qb, vb, qws, kws, vtws, nullptr, nullptr);
    // one block per bh, 8-XCD swizzled (768 = 8*96)
    attn_kernel<<<768, 256, 0, stream>>>(qws, kws, vtws, rpbm, aout);
    gemm_kernel<<<8 * 13 * 6, 256, 0, stream>>>(aout, pwbf, 768, 1, nullptr, nullptr, nullptr, nullptr, nullptr, pb, out);
}

// Round 11
// 159.052 us; speedup vs baseline: 2.3446x; 1.1581x over previous
//
#include <hip/hip_runtime.h>
#include <hip/hip_bf16.h>
#include <stdint.h>

typedef __attribute__((ext_vector_type(8))) short bf16x8_t;
typedef __attribute__((ext_vector_type(4))) float f32x4_t;
typedef unsigned int u32;
typedef unsigned short u16;
typedef u32 __attribute__((address_space(3))) lds_u32;
typedef u32 __attribute__((address_space(1))) gbl_u32;

#define NUM_H 12
#define NTOK 196
#define NBATCH 64
#define CDIM 768
#define VTS 224    // V^T global token stride
#define VLS 232    // V^T LDS token stride (bank-friendly)
#define RPS 208    // rpb transposed pad (cols and qr)

__device__ __forceinline__ u16 f2bf(float f) {
    u32 u = __float_as_uint(f);
    u32 r = u + 0x7FFFu + ((u >> 16) & 1u);
    return (u16)(r >> 16);
}

// ---------------- fp32 -> bf16 convert ----------------
__global__ void cvt_kernel(const float* __restrict__ in, u16* __restrict__ out, int n) {
    int n4 = n >> 2;
    for (int i = blockIdx.x * blockDim.x + threadIdx.x; i < n4; i += gridDim.x * blockDim.x) {
        float4 v = ((const float4*)in)[i];
        ushort4 o;
        o.x = f2bf(v.x); o.y = f2bf(v.y); o.z = f2bf(v.z); o.w = f2bf(v.w);
        ((ushort4*)out)[i] = o;
    }
}

// ---------------- rpb expand (transposed): [729][12] -> [12][col 208][qr 208] f32 ----
__global__ void rpb_kernel(const float* __restrict__ table, const int* __restrict__ idx,
                           float* __restrict__ rpbt) {
    int ij = blockIdx.x * 256 + threadIdx.x;
    if (ij < NTOK * NTOK) {
        const int qr = ij / NTOK, col = ij - qr * NTOK;
        const int rp = idx[ij];
        #pragma unroll
        for (int h = 0; h < NUM_H; h++)
            rpbt[((size_t)h * RPS + col) * RPS + qr] = table[rp * NUM_H + h];
    }
}

// ---------------- GEMM: C[M,N] = A[M,K] @ W[N,K]^T  (bf16 in, epilogue per mode) ----
// XCD bm-strip grid; triple-buffered LDS, two stages in flight.
// SINGLE barrier per K-step: with 3 buffers stage(kt+2) never aliases the buffer
// read at kt, and every ds_read is consumed by an MFMA in-iteration (compiler
// inserts the lgkmcnt), so the post-MFMA lgkm+barrier pair is removable. The
// stage is issued AFTER the barrier so its DMA overlaps ds_read+MFMA.
__global__ __launch_bounds__(256, 3) void gemm_kernel(
    const u16* __restrict__ A, const u16* __restrict__ W, int K, int mode,
    const float* __restrict__ bias_q, const float* __restrict__ bias_v,
    u16* __restrict__ oq, u16* __restrict__ ok, u16* __restrict__ ovt,
    const float* __restrict__ pbias, float* __restrict__ of) {
    __shared__ __align__(16) u16 lds[3][2][4096]; // [buf][A/B][128*32]
    const int tid = threadIdx.x;
    const int wave = tid >> 6, lane = tid & 63;
    const int wr = wave >> 1, wc = wave & 1;
    const int bid = blockIdx.x;
    const int xcd = bid & 7, i = bid >> 3;
    const int i13 = i / 13;
    const int bm = xcd * 13 + (i - i13 * 13);
    const int bn = i13;
    if (bm >= 98) return; // pad blocks (uniform per block, before any barrier)

    f32x4_t acc[4][4];
    #pragma unroll
    for (int ii = 0; ii < 4; ii++)
        #pragma unroll
        for (int jj = 0; jj < 4; jj++) acc[ii][jj] = f32x4_t{0.f, 0.f, 0.f, 0.f};

    auto stage = [&](int buf, int kt) {
        const int k0 = kt * 32;
        const int su = (lane & 3) ^ ((lane >> 2) & 3); // swizzled source 16B-unit
        #pragma unroll
        for (int c2 = 0; c2 < 2; c2++) {
            const int c = wave * 2 + c2;
            {
                const int row = bm * 128 + c * 16 + (lane >> 2);
                const u16* src = A + (size_t)row * K + k0 + su * 8;
                __builtin_amdgcn_global_load_lds((gbl_u32*)src, (lds_u32*)&lds[buf][0][c * 512], 16, 0, 0);
            }
            {
                const int row = bn * 128 + c * 16 + (lane >> 2);
                const u16* src = W + (size_t)row * K + k0 + su * 8;
                __builtin_amdgcn_global_load_lds((gbl_u32*)src, (lds_u32*)&lds[buf][1][c * 512], 16, 0, 0);
            }
        }
    };

    const int NKT = K >> 5; // 24
    stage(0, 0);
    if (NKT > 1) stage(1, 1);
    for (int kt = 0; kt < NKT; ++kt) {
        const int buf = kt % 3;
        if (kt + 1 < NKT) {
            // tile kt's 4 loads landed; tile kt+1's 4 may stay in flight
            asm volatile("s_waitcnt vmcnt(4)" ::: "memory");
        } else {
            asm volatile("s_waitcnt vmcnt(0)" ::: "memory");
        }
        __builtin_amdgcn_s_barrier(); // all waves: tile kt resident; reads of buf(kt-?) done
        if (kt + 2 < NKT) stage((kt + 2) % 3, kt + 2); // DMA overlaps compute below
        bf16x8_t af[4], bfr[4];
        #pragma unroll
        for (int mt = 0; mt < 4; mt++) {
            const int r = wr * 64 + mt * 16 + (lane & 15);
            const int u = (lane >> 4) ^ (r & 3);
            af[mt] = *(const bf16x8_t*)&lds[buf][0][r * 32 + u * 8];
        }
        #pragma unroll
        for (int nt = 0; nt < 4; nt++) {
            const int r = wc * 64 + nt * 16 + (lane & 15);
            const int u = (lane >> 4) ^ (r & 3);
            bfr[nt] = *(const bf16x8_t*)&lds[buf][1][r * 32 + u * 8];
        }
        __builtin_amdgcn_s_setprio(1);
        #pragma unroll
        for (int mt = 0; mt < 4; mt++)
            #pragma unroll
            for (int nt = 0; nt < 4; nt++)
                acc[mt][nt] = __builtin_amdgcn_mfma_f32_16x16x32_bf16(af[mt], bfr[nt], acc[mt][nt], 0, 0, 0);
        __builtin_amdgcn_s_setprio(0);
        // no trailing barrier: ds_reads are drained by the MFMAs' own waitcnts,
        // and the next iteration's pre-barrier orders buffer reuse.
    }

    const int g = lane >> 4;
    if (mode == 0) {
        #pragma unroll
        for (int nt = 0; nt < 4; nt++) {
            const int n = bn * 128 + wc * 64 + nt * 16 + (lane & 15);
            const int which = n / CDIM;
            const int rem = n - which * CDIM;
            const int hh = rem >> 6, d = rem & 63;
            const float bias = (which == 0) ? bias_q[rem] : (which == 2 ? bias_v[rem] : 0.f);
            #pragma unroll
            for (int mt = 0; mt < 4; mt++) {
                const int m0 = bm * 128 + wr * 64 + mt * 16 + 4 * g;
                const int bb = m0 / NTOK, t0 = m0 - bb * NTOK; // r=0..3 stay in-row (196%4==0)
                if (which == 2) {
                    ushort4 vv;
                    vv.x = f2bf(acc[mt][nt][0] + bias);
                    vv.y = f2bf(acc[mt][nt][1] + bias);
                    vv.z = f2bf(acc[mt][nt][2] + bias);
                    vv.w = f2bf(acc[mt][nt][3] + bias);
                    *(ushort4*)&ovt[(((size_t)bb * NUM_H + hh) * 64 + d) * VTS + t0] = vv;
                } else {
                    u16* dst = (which == 0) ? oq : ok;
                    #pragma unroll
                    for (int r = 0; r < 4; r++) {
                        float v = acc[mt][nt][r] + bias;
                        if (which == 0) v *= 0.125f;
                        dst[(((size_t)bb * NUM_H + hh) * NTOK + t0 + r) * 64 + d] = f2bf(v);
                    }
                }
            }
        }
    } else {
        #pragma unroll
        for (int mt = 0; mt < 4; mt++) {
            #pragma unroll
            for (int r = 0; r < 4; r++) {
                const int m = bm * 128 + wr * 64 + mt * 16 + 4 * g + r;
                #pragma unroll
                for (int nt = 0; nt < 4; nt++) {
                    const int n = bn * 128 + wc * 64 + nt * 16 + (lane & 15);
                    of[(size_t)m * CDIM + n] = acc[mt][nt][r] + pbias[n];
                }
            }
        }
    }
}

// ---------------- attention: one block per (b,h); K+V^T DMA-staged in LDS ----------
// r10 + two latency levers:
// (1) split K/V wait: per-wave counted vmcnt guards only the K chunks (V stays in
//     flight), QK^T starts earlier; V drained once before the first PV.
// (2) rpb register-hoist: issue all 13 float4 bias loads BEFORE the QK^T MFMAs so
//     their L2 latency hides under the matrix work.
__global__ __launch_bounds__(256, 2) void attn_kernel(
    const u16* __restrict__ Q, const u16* __restrict__ Kg, const u16* __restrict__ Vt,
    const float* __restrict__ rpbt, u16* __restrict__ O) {
    __shared__ __align__(16) u16 Ks[208 * 64];   // 26624 B, swizzled rows
    __shared__ __align__(16) u16 Vs[64 * VLS];   // 29696 B = 29 chunks
    __shared__ __align__(16) u16 Ps[4][16 * 64]; // per-wave P transpose buffer
    const int lane = threadIdx.x & 63, wave = threadIdx.x >> 6;
    const int bh = (blockIdx.x & 7) + 8 * (blockIdx.x >> 3);
    const int b = bh / NUM_H, h = bh - b * NUM_H;
    const u16* Qb = Q + (size_t)bh * NTOK * 64;
    const u16* Kb = Kg + (size_t)bh * NTOK * 64;
    const u16* Vgb = Vt + (size_t)bh * 64 * VTS;
    const int g = lane >> 4, lc = lane & 15;

    // ---- DMA staging: 26 K-chunks then 29 V-chunks of 1KB, round-robin over waves.
    // Per-wave c ascending -> K insts issue before V insts.
    for (int c = wave; c < 26 + 29; c += 4) {
        if (c < 26) {
            const int row = c * 8 + (lane >> 3);
            const int u = lane & 7;
            const int srow = (row < NTOK) ? row : (NTOK - 1); // clamp pad rows (masked later)
            const u16* src = Kb + srow * 64 + ((u ^ (row & 7)) << 3);
            __builtin_amdgcn_global_load_lds((gbl_u32*)src, (lds_u32*)&Ks[c * 512], 16, 0, 0);
        } else {
            const int p = (c - 26) * 1024 + lane * 16; // byte offset in Vs
            const int d = p / (VLS * 2);
            const int off = p - d * (VLS * 2);
            const u16* src = (off < VTS * 2) ? (Vgb + d * VTS + (off >> 1)) : Vgb; // clamp pad tail
            __builtin_amdgcn_global_load_lds((gbl_u32*)src, (lds_u32*)((char*)Vs + (c - 26) * 1024), 16, 0, 0);
        }
    }
    // V-inst counts per wave: w0=7, w1=7, w2=8, w3=7 -> waiting that many leaves
    // only V outstanding, i.e. all K chunks landed.
    if (wave == 2) asm volatile("s_waitcnt vmcnt(8)" ::: "memory");
    else           asm volatile("s_waitcnt vmcnt(7)" ::: "memory");
    __builtin_amdgcn_s_barrier(); // all waves' K resident; V still in flight

    bool vpending = true;
    // ---- per-wave tile loop ----
    for (int qt = wave; qt < 13; qt += 4) {
        const float* rpbc = rpbt + ((size_t)h * RPS + lc) * RPS + qt * 16 + 4 * g;
        // Q fragments
        bf16x8_t qf[2];
        const int qrow_f = qt * 16 + lc;
        #pragma unroll
        for (int kk = 0; kk < 2; kk++) {
            if (qrow_f < NTOK) qf[kk] = *(const bf16x8_t*)(Qb + qrow_f * 64 + kk * 32 + g * 8);
            else qf[kk] = bf16x8_t{0, 0, 0, 0, 0, 0, 0, 0};
        }
        // rpb prefetch: issue all 13 float4 loads before the MFMA block
        float4 rp13[13];
        #pragma unroll
        for (int nt = 0; nt < 13; nt++) rp13[nt] = *(const float4*)(rpbc + nt * 16 * RPS);
        // S = Q K^T from LDS
        f32x4_t s[13];
        #pragma unroll
        for (int nt = 0; nt < 13; nt++) s[nt] = f32x4_t{0.f, 0.f, 0.f, 0.f};
        #pragma unroll
        for (int nt = 0; nt < 13; nt++) {
            #pragma unroll
            for (int kk = 0; kk < 2; kk++) {
                const int kr = nt * 16 + lc;
                const int u = (kk * 4 + g) ^ (kr & 7);
                bf16x8_t kf = *(const bf16x8_t*)&Ks[kr * 64 + u * 8];
                s[nt] = __builtin_amdgcn_mfma_f32_16x16x32_bf16(qf[kk], kf, s[nt], 0, 0, 0);
            }
        }
        // + rpb, mask, row max
        float mx[4] = {-3e38f, -3e38f, -3e38f, -3e38f};
        #pragma unroll
        for (int nt = 0; nt < 13; nt++) {
            const int col = nt * 16 + lc;
            const float rpv[4] = {rp13[nt].x, rp13[nt].y, rp13[nt].z, rp13[nt].w};
            #pragma unroll
            for (int r = 0; r < 4; r++) {
                const int qr = qt * 16 + 4 * g + r;
                float v;
                if (col < NTOK && qr < NTOK) v = s[nt][r] + rpv[r];
                else v = -1e30f;
                s[nt][r] = v;
                mx[r] = fmaxf(mx[r], v);
            }
        }
        #pragma unroll
        for (int r = 0; r < 4; r++) {
            mx[r] = fmaxf(mx[r], __shfl_xor(mx[r], 1));
            mx[r] = fmaxf(mx[r], __shfl_xor(mx[r], 2));
            mx[r] = fmaxf(mx[r], __shfl_xor(mx[r], 4));
            mx[r] = fmaxf(mx[r], __shfl_xor(mx[r], 8));
        }
        float sm[4] = {0.f, 0.f, 0.f, 0.f};
        #pragma unroll
        for (int nt = 0; nt < 13; nt++)
            #pragma unroll
            for (int r = 0; r < 4; r++) {
                float p = __expf(s[nt][r] - mx[r]);
                s[nt][r] = p;
                sm[r] += p;
            }
        float inv[4];
        #pragma unroll
        for (int r = 0; r < 4; r++) {
            sm[r] += __shfl_xor(sm[r], 1);
            sm[r] += __shfl_xor(sm[r], 2);
            sm[r] += __shfl_xor(sm[r], 4);
            sm[r] += __shfl_xor(sm[r], 8);
            inv[r] = 1.f / sm[r];
        }

        if (vpending) { // V landed? drain once before the first PV (each wave hits once)
            asm volatile("s_waitcnt vmcnt(0)" ::: "memory");
            __builtin_amdgcn_s_barrier();
            vpending = false;
        }

        // O = P V via Ps LDS transpose; V from LDS (stride VLS)
        f32x4_t o4[4];
        #pragma unroll
        for (int dt = 0; dt < 4; dt++) o4[dt] = f32x4_t{0.f, 0.f, 0.f, 0.f};
        for (int kc = 0; kc < 4; kc++) {
            #pragma unroll
            for (int ntl = 0; ntl < 4; ntl++) {
                const int nt = kc * 4 + ntl;
                const int kl = ntl * 16 + lc;
                #pragma unroll
                for (int r = 0; r < 4; r++) {
                    const int rr = 4 * g + r;
                    u16 pv = 0;
                    if (nt < 13) pv = f2bf(s[nt][r]);
                    Ps[wave][rr * 64 + (((kl >> 3) ^ (rr & 7)) << 3) + (kl & 7)] = pv;
                }
            }
            asm volatile("s_waitcnt lgkmcnt(0)" ::: "memory");
            const int nsteps = (kc < 3) ? 2 : 1;
            for (int ks = 0; ks < nsteps; ks++) {
                const int rr = lc;
                const int u = (ks * 4 + g) ^ (rr & 7);
                bf16x8_t pf = *(const bf16x8_t*)&Ps[wave][rr * 64 + u * 8];
                #pragma unroll
                for (int dt = 0; dt < 4; dt++) {
                    const int dcol = dt * 16 + lc;
                    const int kb = kc * 64 + ks * 32 + g * 8;
                    bf16x8_t vf = *(const bf16x8_t*)&Vs[dcol * VLS + kb];
                    o4[dt] = __builtin_amdgcn_mfma_f32_16x16x32_bf16(pf, vf, o4[dt], 0, 0, 0);
                }
            }
            asm volatile("" ::: "memory"); // order next kc's Ps writes after this kc's reads
        }
        // epilogue: Out[b][qr][h*64+d] bf16
        #pragma unroll
        for (int dt = 0; dt < 4; dt++)
            #pragma unroll
            for (int r = 0; r < 4; r++) {
                const int qr = qt * 16 + 4 * g + r;
                if (qr < NTOK)
                    O[((size_t)b * NTOK + qr) * CDIM + h * 64 + dt * 16 + lc] = f2bf(o4[dt][r] * inv[r]);
            }
    }
}

extern "C" void kernel_launch(void* const* d_in, const int* in_sizes, int n_in,
                              void* d_out, int out_size, void* d_ws, size_t ws_size,
                              hipStream_t stream) {
    const float* x = (const float*)d_in[0];
    const float* qkvw = (const float*)d_in[1];
    const float* qb = (const float*)d_in[2];
    const float* vb = (const float*)d_in[3];
    const float* rpbt = (const float*)d_in[4];
    const int* rpi = (const int*)d_in[5];
    const float* pw = (const float*)d_in[6];
    const float* pb = (const float*)d_in[7];
    float* out = (float*)d_out;

    char* ws = (char*)d_ws;
    size_t off = 0;
    auto alloc = [&](size_t bytes) {
        void* p = ws + off;
        off += (bytes + 255) & ~(size_t)255;
        return p;
    };
    const size_t MROWS = 12544; // 64*196
    u16* xbf = (u16*)alloc(MROWS * 768 * 2);
    u16* wbf = (u16*)alloc((size_t)2304 * 768 * 2);
    u16* pwbf = (u16*)alloc((size_t)768 * 768 * 2);
    u16* qws = (u16*)alloc(MROWS * 768 * 2);
    u16* kws = (u16*)alloc(MROWS * 768 * 2);
    u16* vtws = (u16*)alloc((size_t)768 * 64 * VTS * 2 + 256); // V^T [bh][64][VTS] (+slack)
    u16* aout = (u16*)alloc(MROWS * 768 * 2);
    float* rpbm = (float*)alloc((size_t)NUM_H * RPS * RPS * 4 + 256); // transposed [h][col][qr] (+slack)

    cvt_kernel<<<2048, 256, 0, stream>>>(x, xbf, 12544 * 768);
    cvt_kernel<<<1024, 256, 0, stream>>>(qkvw, wbf, 2304 * 768);
    cvt_kernel<<<512, 256, 0, stream>>>(pw, pwbf, 768 * 768);
    rpb_kernel<<<(196 * 196 + 255) / 256, 256, 0, stream>>>(rpbt, rpi, rpbm);
    // XCD-swizzled 1D grids: 8 XCDs * 13 bm-strip * nbn  (bm>=98 pad blocks exit)
    gemm_kernel<<<8 * 13 * 18, 256, 0, stream>>>(xbf, wbf, 768, 0, qb, vb, qws, kws, vtws, nullptr, nullptr);
    // one block per bh, 8-XCD swizzled (768 = 8*96)
    attn_kernel<<<768, 256, 0, stream>>>(qws, kws, vtws, rpbm, aout);
    gemm_kernel<<<8 * 13 * 6, 256, 0, stream>>>(aout, pwbf, 768, 1, nullptr, nullptr, nullptr, nullptr, nullptr, pb, out);
}

// Round 12
// 153.929 us; speedup vs baseline: 2.4227x; 1.0333x over previous
//
#include <hip/hip_runtime.h>
#include <hip/hip_bf16.h>
#include <stdint.h>

typedef __attribute__((ext_vector_type(8))) short bf16x8_t;
typedef __attribute__((ext_vector_type(4))) float f32x4_t;
typedef unsigned int u32;
typedef unsigned short u16;
typedef u32 __attribute__((address_space(3))) lds_u32;
typedef u32 __attribute__((address_space(1))) gbl_u32;

#define NUM_H 12
#define NTOK 196
#define NBATCH 64
#define CDIM 768
#define VTS 224    // V^T global token stride
#define VLS 232    // V^T LDS token stride (bank-friendly)
#define RPS 208    // rpb transposed pad (cols and qr)

__device__ __forceinline__ u16 f2bf(float f) {
    u32 u = __float_as_uint(f);
    u32 r = u + 0x7FFFu + ((u >> 16) & 1u);
    return (u16)(r >> 16);
}

// ---------------- fp32 -> bf16 convert, 3 arrays in one launch ----------------
__global__ void cvt3_kernel(const float* __restrict__ a, u16* __restrict__ oa, int na4,
                            const float* __restrict__ b, u16* __restrict__ ob, int nb4,
                            const float* __restrict__ c, u16* __restrict__ oc, int nc4) {
    const int total = na4 + nb4 + nc4;
    for (int i = blockIdx.x * blockDim.x + threadIdx.x; i < total; i += gridDim.x * blockDim.x) {
        const float* src;
        u16* dst;
        int j = i;
        if (j < na4) { src = a; dst = oa; }
        else if ((j -= na4) < nb4) { src = b; dst = ob; }
        else { j -= nb4; src = c; dst = oc; }
        float4 v = ((const float4*)src)[j];
        ushort4 o;
        o.x = f2bf(v.x); o.y = f2bf(v.y); o.z = f2bf(v.z); o.w = f2bf(v.w);
        ((ushort4*)dst)[j] = o;
    }
}

// ---------------- rpb expand (transposed): [729][12] -> [12][col 208][qr 208] f32 ----
__global__ void rpb_kernel(const float* __restrict__ table, const int* __restrict__ idx,
                           float* __restrict__ rpbt) {
    int ij = blockIdx.x * 256 + threadIdx.x;
    if (ij < NTOK * NTOK) {
        const int qr = ij / NTOK, col = ij - qr * NTOK;
        const int rp = idx[ij];
        #pragma unroll
        for (int h = 0; h < NUM_H; h++)
            rpbt[((size_t)h * RPS + col) * RPS + qr] = table[rp * NUM_H + h];
    }
}

// ---------------- GEMM: C[M,N] = A[M,K] @ W[N,K]^T  (bf16 in, epilogue per mode) ----
// XCD bm-strip grid; triple-buffered LDS, two stages in flight, single barrier/step.
// LDS swizzle upgraded to perfect 2-way (free): read u = g ^ (r&3) ^ ((r>>2)&3),
// source su = (lane&3)^((lane>>2)&3)^((lane>>4)&3)  [r11: 4-way -> 5.4M conflicts].
// mode-0 q/k epilogue: LDS-bounce -> 8 coalesced dwordx4 row stores per wave.
__global__ __launch_bounds__(256, 3) void gemm_kernel(
    const u16* __restrict__ A, const u16* __restrict__ W, int K, int mode,
    const float* __restrict__ bias_q, const float* __restrict__ bias_v,
    u16* __restrict__ oq, u16* __restrict__ ok, u16* __restrict__ ovt,
    const float* __restrict__ pbias, float* __restrict__ of) {
    __shared__ __align__(16) u16 lds[3][2][4096]; // [buf][A/B][128*32]
    const int tid = threadIdx.x;
    const int wave = tid >> 6, lane = tid & 63;
    const int wr = wave >> 1, wc = wave & 1;
    const int bid = blockIdx.x;
    const int xcd = bid & 7, i = bid >> 3;
    const int i13 = i / 13;
    const int bm = xcd * 13 + (i - i13 * 13);
    const int bn = i13;
    if (bm >= 98) return; // pad blocks (uniform per block, before any barrier)

    f32x4_t acc[4][4];
    #pragma unroll
    for (int ii = 0; ii < 4; ii++)
        #pragma unroll
        for (int jj = 0; jj < 4; jj++) acc[ii][jj] = f32x4_t{0.f, 0.f, 0.f, 0.f};

    auto stage = [&](int buf, int kt) {
        const int k0 = kt * 32;
        // perfect 2-way swizzled source 16B-unit
        const int su = (lane & 3) ^ ((lane >> 2) & 3) ^ ((lane >> 4) & 3);
        #pragma unroll
        for (int c2 = 0; c2 < 2; c2++) {
            const int c = wave * 2 + c2;
            {
                const int row = bm * 128 + c * 16 + (lane >> 2);
                const u16* src = A + (size_t)row * K + k0 + su * 8;
                __builtin_amdgcn_global_load_lds((gbl_u32*)src, (lds_u32*)&lds[buf][0][c * 512], 16, 0, 0);
            }
            {
                const int row = bn * 128 + c * 16 + (lane >> 2);
                const u16* src = W + (size_t)row * K + k0 + su * 8;
                __builtin_amdgcn_global_load_lds((gbl_u32*)src, (lds_u32*)&lds[buf][1][c * 512], 16, 0, 0);
            }
        }
    };

    const int NKT = K >> 5; // 24
    stage(0, 0);
    if (NKT > 1) stage(1, 1);
    for (int kt = 0; kt < NKT; ++kt) {
        const int buf = kt % 3;
        if (kt + 1 < NKT) {
            asm volatile("s_waitcnt vmcnt(4)" ::: "memory");
        } else {
            asm volatile("s_waitcnt vmcnt(0)" ::: "memory");
        }
        __builtin_amdgcn_s_barrier(); // all waves: tile kt resident; reads of reuse-buf done
        if (kt + 2 < NKT) stage((kt + 2) % 3, kt + 2); // DMA overlaps compute below
        bf16x8_t af[4], bfr[4];
        #pragma unroll
        for (int mt = 0; mt < 4; mt++) {
            const int r = wr * 64 + mt * 16 + (lane & 15);
            const int u = (lane >> 4) ^ (r & 3) ^ ((r >> 2) & 3);
            af[mt] = *(const bf16x8_t*)&lds[buf][0][r * 32 + u * 8];
        }
        #pragma unroll
        for (int nt = 0; nt < 4; nt++) {
            const int r = wc * 64 + nt * 16 + (lane & 15);
            const int u = (lane >> 4) ^ (r & 3) ^ ((r >> 2) & 3);
            bfr[nt] = *(const bf16x8_t*)&lds[buf][1][r * 32 + u * 8];
        }
        __builtin_amdgcn_s_setprio(1);
        #pragma unroll
        for (int mt = 0; mt < 4; mt++)
            #pragma unroll
            for (int nt = 0; nt < 4; nt++)
                acc[mt][nt] = __builtin_amdgcn_mfma_f32_16x16x32_bf16(af[mt], bfr[nt], acc[mt][nt], 0, 0, 0);
        __builtin_amdgcn_s_setprio(0);
    }
    // After barrier(NKT-1) every wave only reads buf2; epilogue wave-tiles live in
    // buf0+buf1 (wave*4096 u16, 4*8KB = lds[0]+lds[1]) -> no race, no barrier needed.

    const int g = lane >> 4, lc = lane & 15;
    if (mode == 0) {
        const int n_base = bn * 128 + wc * 64;    // 64-aligned window, single region
        const int which = n_base / CDIM;
        const int rem0 = n_base - which * CDIM;
        if (which == 2) {
            // V^T path (8B ushort4 stores) unchanged
            #pragma unroll
            for (int nt = 0; nt < 4; nt++) {
                const int rem = rem0 + nt * 16 + lc;
                const int hh = rem >> 6, d = rem & 63;
                const float bias = bias_v[rem];
                #pragma unroll
                for (int mt = 0; mt < 4; mt++) {
                    const int m0 = bm * 128 + wr * 64 + mt * 16 + 4 * g;
                    const int bb = m0 / NTOK, t0 = m0 - bb * NTOK; // r=0..3 in-row (196%4==0)
                    ushort4 vv;
                    vv.x = f2bf(acc[mt][nt][0] + bias);
                    vv.y = f2bf(acc[mt][nt][1] + bias);
                    vv.z = f2bf(acc[mt][nt][2] + bias);
                    vv.w = f2bf(acc[mt][nt][3] + bias);
                    *(ushort4*)&ovt[(((size_t)bb * NUM_H + hh) * 64 + d) * VTS + t0] = vv;
                }
            }
        } else {
            // q/k: stage wave's 64x64 bf16 tile in LDS (swizzled), then 8 coalesced
            // dwordx4 full-row stores.
            u16* tile = ((u16*)lds) + wave * 4096;
            const float scale = (which == 0) ? 0.125f : 1.f;
            #pragma unroll
            for (int nt = 0; nt < 4; nt++) {
                const int rem = rem0 + nt * 16 + lc;
                const float bias = (which == 0) ? bias_q[rem] : 0.f;
                const int nl = nt * 16 + lc;
                #pragma unroll
                for (int mt = 0; mt < 4; mt++) {
                    #pragma unroll
                    for (int r = 0; r < 4; r++) {
                        const int ml = mt * 16 + 4 * g + r;
                        const int nsw = (nl & 7) | ((((nl >> 3) ^ (ml & 7)) & 7) << 3);
                        tile[ml * 64 + nsw] = f2bf((acc[mt][nt][r] + bias) * scale);
                    }
                }
            }
            asm volatile("s_waitcnt lgkmcnt(0)" ::: "memory");
            u16* dst = (which == 0) ? oq : ok;
            const int hh = rem0 >> 6;
            #pragma unroll
            for (int it = 0; it < 8; it++) {
                const int ml = it * 8 + (lane >> 3);
                const int u = lane & 7;
                const int usw = u ^ (ml & 7);
                bf16x8_t v = *(const bf16x8_t*)&tile[ml * 64 + usw * 8];
                const int mg = bm * 128 + wr * 64 + ml;
                const int bb = mg / NTOK, t = mg - bb * NTOK;
                *(bf16x8_t*)&dst[(((size_t)bb * NUM_H + hh) * NTOK + t) * 64 + u * 8] = v;
            }
        }
    } else {
        #pragma unroll
        for (int mt = 0; mt < 4; mt++) {
            #pragma unroll
            for (int r = 0; r < 4; r++) {
                const int m = bm * 128 + wr * 64 + mt * 16 + 4 * g + r;
                #pragma unroll
                for (int nt = 0; nt < 4; nt++) {
                    const int n = bn * 128 + wc * 64 + nt * 16 + lc;
                    of[(size_t)m * CDIM + n] = acc[mt][nt][r] + pbias[n];
                }
            }
        }
    }
}

// ---------------- attention: one block per (b,h); K+V^T DMA-staged in LDS ----------
// (unchanged from r11: split K/V vmcnt wait + rpb register-hoist)
__global__ __launch_bounds__(256, 2) void attn_kernel(
    const u16* __restrict__ Q, const u16* __restrict__ Kg, const u16* __restrict__ Vt,
    const float* __restrict__ rpbt, u16* __restrict__ O) {
    __shared__ __align__(16) u16 Ks[208 * 64];   // 26624 B, swizzled rows
    __shared__ __align__(16) u16 Vs[64 * VLS];   // 29696 B = 29 chunks
    __shared__ __align__(16) u16 Ps[4][16 * 64]; // per-wave P transpose buffer
    const int lane = threadIdx.x & 63, wave = threadIdx.x >> 6;
    const int bh = (blockIdx.x & 7) + 8 * (blockIdx.x >> 3);
    const int b = bh / NUM_H, h = bh - b * NUM_H;
    const u16* Qb = Q + (size_t)bh * NTOK * 64;
    const u16* Kb = Kg + (size_t)bh * NTOK * 64;
    const u16* Vgb = Vt + (size_t)bh * 64 * VTS;
    const int g = lane >> 4, lc = lane & 15;

    for (int c = wave; c < 26 + 29; c += 4) {
        if (c < 26) {
            const int row = c * 8 + (lane >> 3);
            const int u = lane & 7;
            const int srow = (row < NTOK) ? row : (NTOK - 1);
            const u16* src = Kb + srow * 64 + ((u ^ (row & 7)) << 3);
            __builtin_amdgcn_global_load_lds((gbl_u32*)src, (lds_u32*)&Ks[c * 512], 16, 0, 0);
        } else {
            const int p = (c - 26) * 1024 + lane * 16;
            const int d = p / (VLS * 2);
            const int off = p - d * (VLS * 2);
            const u16* src = (off < VTS * 2) ? (Vgb + d * VTS + (off >> 1)) : Vgb;
            __builtin_amdgcn_global_load_lds((gbl_u32*)src, (lds_u32*)((char*)Vs + (c - 26) * 1024), 16, 0, 0);
        }
    }
    if (wave == 2) asm volatile("s_waitcnt vmcnt(8)" ::: "memory");
    else           asm volatile("s_waitcnt vmcnt(7)" ::: "memory");
    __builtin_amdgcn_s_barrier(); // all waves' K resident; V still in flight

    bool vpending = true;
    for (int qt = wave; qt < 13; qt += 4) {
        const float* rpbc = rpbt + ((size_t)h * RPS + lc) * RPS + qt * 16 + 4 * g;
        bf16x8_t qf[2];
        const int qrow_f = qt * 16 + lc;
        #pragma unroll
        for (int kk = 0; kk < 2; kk++) {
            if (qrow_f < NTOK) qf[kk] = *(const bf16x8_t*)(Qb + qrow_f * 64 + kk * 32 + g * 8);
            else qf[kk] = bf16x8_t{0, 0, 0, 0, 0, 0, 0, 0};
        }
        float4 rp13[13];
        #pragma unroll
        for (int nt = 0; nt < 13; nt++) rp13[nt] = *(const float4*)(rpbc + nt * 16 * RPS);
        f32x4_t s[13];
        #pragma unroll
        for (int nt = 0; nt < 13; nt++) s[nt] = f32x4_t{0.f, 0.f, 0.f, 0.f};
        #pragma unroll
        for (int nt = 0; nt < 13; nt++) {
            #pragma unroll
            for (int kk = 0; kk < 2; kk++) {
                const int kr = nt * 16 + lc;
                const int u = (kk * 4 + g) ^ (kr & 7);
                bf16x8_t kf = *(const bf16x8_t*)&Ks[kr * 64 + u * 8];
                s[nt] = __builtin_amdgcn_mfma_f32_16x16x32_bf16(qf[kk], kf, s[nt], 0, 0, 0);
            }
        }
        float mx[4] = {-3e38f, -3e38f, -3e38f, -3e38f};
        #pragma unroll
        for (int nt = 0; nt < 13; nt++) {
            const int col = nt * 16 + lc;
            const float rpv[4] = {rp13[nt].x, rp13[nt].y, rp13[nt].z, rp13[nt].w};
            #pragma unroll
            for (int r = 0; r < 4; r++) {
                const int qr = qt * 16 + 4 * g + r;
                float v;
                if (col < NTOK && qr < NTOK) v = s[nt][r] + rpv[r];
                else v = -1e30f;
                s[nt][r] = v;
                mx[r] = fmaxf(mx[r], v);
            }
        }
        #pragma unroll
        for (int r = 0; r < 4; r++) {
            mx[r] = fmaxf(mx[r], __shfl_xor(mx[r], 1));
            mx[r] = fmaxf(mx[r], __shfl_xor(mx[r], 2));
            mx[r] = fmaxf(mx[r], __shfl_xor(mx[r], 4));
            mx[r] = fmaxf(mx[r], __shfl_xor(mx[r], 8));
        }
        float sm[4] = {0.f, 0.f, 0.f, 0.f};
        #pragma unroll
        for (int nt = 0; nt < 13; nt++)
            #pragma unroll
            for (int r = 0; r < 4; r++) {
                float p = __expf(s[nt][r] - mx[r]);
                s[nt][r] = p;
                sm[r] += p;
            }
        float inv[4];
        #pragma unroll
        for (int r = 0; r < 4; r++) {
            sm[r] += __shfl_xor(sm[r], 1);
            sm[r] += __shfl_xor(sm[r], 2);
            sm[r] += __shfl_xor(sm[r], 4);
            sm[r] += __shfl_xor(sm[r], 8);
            inv[r] = 1.f / sm[r];
        }

        if (vpending) {
            asm volatile("s_waitcnt vmcnt(0)" ::: "memory");
            __builtin_amdgcn_s_barrier();
            vpending = false;
        }

        f32x4_t o4[4];
        #pragma unroll
        for (int dt = 0; dt < 4; dt++) o4[dt] = f32x4_t{0.f, 0.f, 0.f, 0.f};
        for (int kc = 0; kc < 4; kc++) {
            #pragma unroll
            for (int ntl = 0; ntl < 4; ntl++) {
                const int nt = kc * 4 + ntl;
                const int kl = ntl * 16 + lc;
                #pragma unroll
                for (int r = 0; r < 4; r++) {
                    const int rr = 4 * g + r;
                    u16 pv = 0;
                    if (nt < 13) pv = f2bf(s[nt][r]);
                    Ps[wave][rr * 64 + (((kl >> 3) ^ (rr & 7)) << 3) + (kl & 7)] = pv;
                }
            }
            asm volatile("s_waitcnt lgkmcnt(0)" ::: "memory");
            const int nsteps = (kc < 3) ? 2 : 1;
            for (int ks = 0; ks < nsteps; ks++) {
                const int rr = lc;
                const int u = (ks * 4 + g) ^ (rr & 7);
                bf16x8_t pf = *(const bf16x8_t*)&Ps[wave][rr * 64 + u * 8];
                #pragma unroll
                for (int dt = 0; dt < 4; dt++) {
                    const int dcol = dt * 16 + lc;
                    const int kb = kc * 64 + ks * 32 + g * 8;
                    bf16x8_t vf = *(const bf16x8_t*)&Vs[dcol * VLS + kb];
                    o4[dt] = __builtin_amdgcn_mfma_f32_16x16x32_bf16(pf, vf, o4[dt], 0, 0, 0);
                }
            }
            asm volatile("" ::: "memory");
        }
        #pragma unroll
        for (int dt = 0; dt < 4; dt++)
            #pragma unroll
            for (int r = 0; r < 4; r++) {
                const int qr = qt * 16 + 4 * g + r;
                if (qr < NTOK)
                    O[((size_t)b * NTOK + qr) * CDIM + h * 64 + dt * 16 + lc] = f2bf(o4[dt][r] * inv[r]);
            }
    }
}

extern "C" void kernel_launch(void* const* d_in, const int* in_sizes, int n_in,
                              void* d_out, int out_size, void* d_ws, size_t ws_size,
                              hipStream_t stream) {
    const float* x = (const float*)d_in[0];
    const float* qkvw = (const float*)d_in[1];
    const float* qb = (const float*)d_in[2];
    const float* vb = (const float*)d_in[3];
    const float* rpbt = (const float*)d_in[4];
    const int* rpi = (const int*)d_in[5];
    const float* pw = (const float*)d_in[6];
    const float* pb = (const float*)d_in[7];
    float* out = (float*)d_out;

    char* ws = (char*)d_ws;
    size_t off = 0;
    auto alloc = [&](size_t bytes) {
        void* p = ws + off;
        off += (bytes + 255) & ~(size_t)255;
        return p;
    };
    const size_t MROWS = 12544; // 64*196
    u16* xbf = (u16*)alloc(MROWS * 768 * 2);
    u16* wbf = (u16*)alloc((size_t)2304 * 768 * 2);
    u16* pwbf = (u16*)alloc((size_t)768 * 768 * 2);
    u16* qws = (u16*)alloc(MROWS * 768 * 2);
    u16* kws = (u16*)alloc(MROWS * 768 * 2);
    u16* vtws = (u16*)alloc((size_t)768 * 64 * VTS * 2 + 256); // V^T [bh][64][VTS] (+slack)
    u16* aout = (u16*)alloc(MROWS * 768 * 2);
    float* rpbm = (float*)alloc((size_t)NUM_H * RPS * RPS * 4 + 256); // transposed [h][col][qr] (+slack)

    cvt3_kernel<<<2048, 256, 0, stream>>>(x, xbf, (12544 * 768) / 4,
                                          qkvw, wbf, (2304 * 768) / 4,
                                          pw, pwbf, (768 * 768) / 4);
    rpb_kernel<<<(196 * 196 + 255) / 256, 256, 0, stream>>>(rpbt, rpi, rpbm);
    // XCD-swizzled 1D grids: 8 XCDs * 13 bm-strip * nbn  (bm>=98 pad blocks exit)
    gemm_kernel<<<8 * 13 * 18, 256, 0, stream>>>(xbf, wbf, 768, 0, qb, vb, qws, kws, vtws, nullptr, nullptr);
    // one block per bh, 8-XCD swizzled (768 = 8*96)
    attn_kernel<<<768, 256, 0, stream>>>(qws, kws, vtws, rpbm, aout);
    gemm_kernel<<<8 * 13 * 6, 256, 0, stream>>>(aout, pwbf, 768, 1, nullptr, nullptr, nullptr, nullptr, nullptr, pb, out);
}